// Round 9
// baseline (59229.321 us; speedup 1.0000x reference)
//
#include <hip/hip_runtime.h>

#define NN    500
#define TT    20000
#define NPAD  512
#define NBLK  8
#define NROW  64        // padded rows per block
#define TPB   512
#define RPT   4         // rows per thread
#define CPT   16        // cols per thread (strided by 32)
#define DTC   0.05f
#define SQDTC 0.22360679774997896f

typedef unsigned int u32x4  __attribute__((ext_vector_type(4)));
typedef unsigned int u32x16 __attribute__((ext_vector_type(16)));

// ---------------------------------------------------------------------------
// Fully-coherent 16B store (sc0 sc1). Packet layout (x, tag, y, tag).
// ---------------------------------------------------------------------------
__device__ __forceinline__ void store_coh_u128(u32x4* p, u32x4 v) {
    asm volatile("global_store_dwordx4 %0, %1, off sc0 sc1" :: "v"(p), "v"(v) : "memory");
}
__device__ __forceinline__ u32x4 load_coh_u128(const u32x4* p) {
    u32x4 v;
    asm volatile("global_load_dwordx4 %0, %1, off sc0 sc1\n\t"
                 "s_waitcnt vmcnt(0)" : "=v"(v) : "v"(p) : "memory");
    return v;
}

// select noise word 2*k+off from the wave's 16-dword scalar block (k = 0..7)
__device__ __forceinline__ float pick8(const u32x16& s, int k, int off) {
    unsigned r = (k < 4)
        ? ((k < 2) ? (k == 0 ? s[0 + off] : s[2 + off]) : (k == 2 ? s[4 + off] : s[6 + off]))
        : ((k < 6) ? (k == 4 ? s[8 + off] : s[10 + off]) : (k == 6 ? s[12 + off] : s[14 + off]));
    return __uint_as_float(r);
}

// ws layout: pub[2][NPAD] of u32x4 = 16 KB
__global__ __launch_bounds__(1024) void hopf_init_ws(u32x4* pub) {
    int i = blockIdx.x * blockDim.x + threadIdx.x;
    if (i < 2 * NPAD) pub[i] = (u32x4){0u, 0u, 0u, 0u};
}

__global__ __launch_bounds__(TPB) void hopf_main(
    const float* __restrict__ sc, const float* __restrict__ x0,
    const float* __restrict__ y0, const float* __restrict__ aa,
    const float* __restrict__ om, const float* __restrict__ noise,
    const float* __restrict__ gg, float* __restrict__ out,
    u32x4* __restrict__ pub)
{
    const int tid  = threadIdx.x;
    const int blk  = blockIdx.x;
    const int cgrp = tid & 31;       // 32 column groups
    const int rgrp = tid >> 5;       // 16 row groups of RPT rows
    const int r0   = blk * NROW + rgrp * RPT;   // padded global row base

    __shared__ __align__(16) float2 xy[NPAD];   // full padded state (x,y)

    // ---- sc slice -> registers.  col(c) = cgrp + 32*c ----
    float scr[RPT][CPT];
#pragma unroll
    for (int r = 0; r < RPT; ++r) {
        int row = r0 + r;
#pragma unroll
        for (int c = 0; c < CPT; ++c) {
            int col = cgrp + 32 * c;
            scr[r][c] = (row < NN && col < NN) ? sc[row * NN + col] : 0.0f;
        }
    }

    // ---- deg per row ----
    float dsum[RPT];
#pragma unroll
    for (int r = 0; r < RPT; ++r) {
        float s = 0.f;
#pragma unroll
        for (int c = 0; c < CPT; ++c) s += scr[r][c];
        dsum[r] = s;
    }
#pragma unroll
    for (int m = 16; m >= 1; m >>= 1) {
#pragma unroll
        for (int r = 0; r < RPT; ++r) dsum[r] += __shfl_xor(dsum[r], m, 32);
    }

    // ---- pin the sc slice (optimizer cannot demote/rematerialize) ----
#pragma unroll
    for (int r = 0; r < RPT; ++r)
#pragma unroll
        for (int c = 0; c < CPT; ++c)
            asm volatile("" : "+v"(scr[r][c]));

    // ---- per-finalize-lane constants (lanes cgrp<RPT own row r0+cgrp) ----
    float a_i = 0.f, om_i = 0.f, deg_i = 0.f;
    int myrow = -1;
    if (cgrp < RPT) {
        int row = r0 + cgrp;
        deg_i = (cgrp == 0) ? dsum[0] : (cgrp == 1) ? dsum[1]
              : (cgrp == 2) ? dsum[2] : dsum[3];
        if (row < NN) { myrow = row; a_i = aa[row]; om_i = om[row]; }
    }
    const float g = gg[0];

    // ---- scalar-pipe noise: each wave's 8 publisher rows are contiguous.
    //      readfirstlane makes the base architecturally wave-uniform (SGPR). ----
    int nb_ = blk * NROW + 8 * (tid >> 6);
    if (nb_ > NN - 8) nb_ = NN - 8;         // clamp in-bounds; ri8 stays 0..7 for real rows
    const int nb = __builtin_amdgcn_readfirstlane(nb_);
    const float* nwav = noise + 2 * (size_t)nb;
    const int ri8 = myrow - nb;             // 0..7 when myrow >= 0

    // ---- initial state into LDS ----
    xy[tid] = (tid < NN) ? make_float2(x0[tid], y0[tid]) : make_float2(0.f, 0.f);
    __syncthreads();

    // persistent ping-pong poll buffers (live across the whole t-loop so an
    // in-flight straggler load can never land in a reused register)
    u32x4 va = {0u, 0u, 0u, 0u}, vb = {0u, 0u, 0u, 0u};

    for (int t = 0; t < TT; ++t) {
        const int p = t & 1;

        // ---- issue this step's noise via SMEM (lgkmcnt, NOT vmcnt) ----
        u32x16 sg;
        unsigned noff = (unsigned)t * (unsigned)(NN * 2 * 4);
        asm volatile("s_load_dwordx16 %0, %1, %2"
                     : "=&s"(sg) : "s"(nwav), "s"(noff) : "memory");

        // ---- partial matvec: 4 rows x 16 strided cols per thread ----
        float2 acc[RPT];
#pragma unroll
        for (int r = 0; r < RPT; ++r) acc[r] = make_float2(0.f, 0.f);
#pragma unroll
        for (int c = 0; c < CPT; ++c) {
            float2 w = xy[cgrp + 32 * c];
#pragma unroll
            for (int r = 0; r < RPT; ++r) {
                acc[r].x += scr[r][c] * w.x;
                acc[r].y += scr[r][c] * w.y;
            }
        }
        // ---- reduce across the 32 column-group lanes ----
#pragma unroll
        for (int m = 16; m >= 1; m >>= 1) {
#pragma unroll
            for (int r = 0; r < RPT; ++r) {
                acc[r].x += __shfl_xor(acc[r].x, m, 32);
                acc[r].y += __shfl_xor(acc[r].y, m, 32);
            }
        }

        // noise surely arrived (issued before matvec); tie sg through the wait
        asm volatile("s_waitcnt lgkmcnt(0)" : "+s"(sg) :: "memory");

        // ---- finalize + publish tagged 16B packet (lanes cgrp<RPT) ----
        if (myrow >= 0) {
            float sx = (cgrp == 0) ? acc[0].x : (cgrp == 1) ? acc[1].x
                     : (cgrp == 2) ? acc[2].x : acc[3].x;
            float sy = (cgrp == 0) ? acc[0].y : (cgrp == 1) ? acc[1].y
                     : (cgrp == 2) ? acc[2].y : acc[3].y;
            float nx = pick8(sg, ri8, 0);
            float ny = pick8(sg, ri8, 1);
            float2 cur = xy[myrow];
            float r2 = cur.x * cur.x + cur.y * cur.y;
            float cx = sx - deg_i * cur.x;
            float cy = sy - deg_i * cur.y;
            float dx = (a_i - r2) * cur.x - om_i * cur.y + g * cx;
            float dy = (a_i - r2) * cur.y + om_i * cur.x + g * cy;
            float xn = cur.x + DTC * dx + SQDTC * nx;
            float yn = cur.y + DTC * dy + SQDTC * ny;
            out[(size_t)t * NN + myrow] = xn;
            u32x4 pkt = { __float_as_uint(xn), (unsigned)(t + 1),
                          __float_as_uint(yn), (unsigned)(t + 1) };
            store_coh_u128(&pub[(size_t)p * NPAD + myrow], pkt);
        }

        if (t == TT - 1) break;   // uniform across grid

        // protect xy: all matvec/finalize reads done before overwrite
        __syncthreads();

        // ---- gather: ping-pong poll, two loads in flight to DISTINCT quads,
        //      vmcnt(1) waits only the older -> sampling period ~RTT/2 ----
        if (tid < NN) {
            const u32x4* slot = &pub[(size_t)p * NPAD + tid];
            const int need = t + 1;
            asm volatile("global_load_dwordx4 %0, %2, off sc0 sc1\n\t"
                         "global_load_dwordx4 %1, %2, off sc0 sc1"
                         : "+v"(va), "+v"(vb) : "v"(slot) : "memory");
            u32x4 res;
            for (;;) {
                asm volatile("s_waitcnt vmcnt(1)" ::: "memory");
                __builtin_amdgcn_sched_barrier(0);
                if ((int)va.y >= need && (int)va.w >= need) { res = va; break; }
                asm volatile("global_load_dwordx4 %0, %1, off sc0 sc1"
                             : "+v"(va) : "v"(slot) : "memory");
                asm volatile("s_waitcnt vmcnt(1)" ::: "memory");
                __builtin_amdgcn_sched_barrier(0);
                if ((int)vb.y >= need && (int)vb.w >= need) { res = vb; break; }
                asm volatile("global_load_dwordx4 %0, %1, off sc0 sc1"
                             : "+v"(vb) : "v"(slot) : "memory");
            }
            xy[tid] = make_float2(__uint_as_float(res.x), __uint_as_float(res.z));
        }
        __syncthreads();
    }

    // keep ping-pong buffers alive to the end: the last straggler load must
    // not land in a register the compiler reused.
    asm volatile("" :: "v"(va), "v"(vb));
}

extern "C" void kernel_launch(void* const* d_in, const int* in_sizes, int n_in,
                              void* d_out, int out_size, void* d_ws, size_t ws_size,
                              hipStream_t stream) {
    const float* sc = (const float*)d_in[0];
    const float* x0 = (const float*)d_in[1];
    const float* y0 = (const float*)d_in[2];
    const float* aa = (const float*)d_in[3];
    const float* om = (const float*)d_in[4];
    const float* nz = (const float*)d_in[5];
    const float* gg = (const float*)d_in[6];
    float* out = (float*)d_out;

    u32x4* pub = (u32x4*)d_ws;   // 2*NPAD*16 = 16 KB

    hipLaunchKernelGGL(hopf_init_ws, dim3(1), dim3(1024), 0, stream, pub);
    hipLaunchKernelGGL(hopf_main, dim3(NBLK), dim3(TPB), 0, stream,
                       sc, x0, y0, aa, om, nz, gg, out, pub);
}

// Round 12
// 44966.214 us; speedup vs baseline: 1.3172x; 1.3172x over previous
//
#include <hip/hip_runtime.h>

#define NN    500
#define TT    20000
#define NPAD  512
#define NBLK  8
#define NROW  64        // padded rows per block
#define TPB   512
#define RPT   4         // rows per thread
#define CPT   16        // cols per thread (strided by 32)
#define DTC   0.05f
#define SQDTC 0.22360679774997896f

typedef unsigned int u32x4 __attribute__((ext_vector_type(4)));

// ---------------------------------------------------------------------------
// Fully-coherent 16B accessors (sc0 sc1 = device/system scope, served at the
// Infinity-Cache coherence point; proven reliable in R2/R5).
// Packet layout (x, tag, y, tag): each 8B half = one data word + one tag.
// ---------------------------------------------------------------------------
__device__ __forceinline__ void store_coh_u128(u32x4* p, u32x4 v) {
    asm volatile("global_store_dwordx4 %0, %1, off sc0 sc1" :: "v"(p), "v"(v) : "memory");
}
__device__ __forceinline__ u32x4 load_coh_u128(const u32x4* p) {
    u32x4 v;
    asm volatile("global_load_dwordx4 %0, %1, off sc0 sc1\n\t"
                 "s_waitcnt vmcnt(0)" : "=v"(v) : "v"(p) : "memory");
    return v;
}

// ws layout: pub[2][NPAD] of u32x4 = 16 KB
__global__ __launch_bounds__(1024) void hopf_init_ws(u32x4* pub) {
    int i = blockIdx.x * blockDim.x + threadIdx.x;
    if (i < 2 * NPAD) pub[i] = (u32x4){0u, 0u, 0u, 0u};
}

__global__ __launch_bounds__(TPB) void hopf_main(
    const float* __restrict__ sc, const float* __restrict__ x0,
    const float* __restrict__ y0, const float* __restrict__ aa,
    const float* __restrict__ om, const float* __restrict__ noise,
    const float* __restrict__ gg, float* __restrict__ out,
    u32x4* __restrict__ pub)
{
    const int tid  = threadIdx.x;
    const int blk  = blockIdx.x;
    const int cgrp = tid & 31;       // 32 column groups
    const int rgrp = tid >> 5;       // 16 row groups of RPT rows
    const int r0   = blk * NROW + rgrp * RPT;   // padded global row base

    __shared__ __align__(16) float2 xy[NPAD];   // full padded state (x,y)

    // ---- sc slice -> registers.  col(c) = cgrp + 32*c ----
    float scr[RPT][CPT];
#pragma unroll
    for (int r = 0; r < RPT; ++r) {
        int row = r0 + r;
#pragma unroll
        for (int c = 0; c < CPT; ++c) {
            int col = cgrp + 32 * c;
            scr[r][c] = (row < NN && col < NN) ? sc[row * NN + col] : 0.0f;
        }
    }

    // ---- deg per row ----
    float dsum[RPT];
#pragma unroll
    for (int r = 0; r < RPT; ++r) {
        float s = 0.f;
#pragma unroll
        for (int c = 0; c < CPT; ++c) s += scr[r][c];
        dsum[r] = s;
    }
#pragma unroll
    for (int m = 16; m >= 1; m >>= 1) {
#pragma unroll
        for (int r = 0; r < RPT; ++r) dsum[r] += __shfl_xor(dsum[r], m, 32);
    }

    // ---- pin the sc slice (optimizer cannot demote/rematerialize) ----
#pragma unroll
    for (int r = 0; r < RPT; ++r)
#pragma unroll
        for (int c = 0; c < CPT; ++c)
            asm volatile("" : "+v"(scr[r][c]));

    // ---- per-finalize-lane constants (lanes cgrp<RPT own row r0+cgrp) ----
    float a_i = 0.f, om_i = 0.f, deg_i = 0.f;
    int myrow = -1;
    if (cgrp < RPT) {
        int row = r0 + cgrp;
        deg_i = (cgrp == 0) ? dsum[0] : (cgrp == 1) ? dsum[1]
              : (cgrp == 2) ? dsum[2] : dsum[3];
        if (row < NN) { myrow = row; a_i = aa[row]; om_i = om[row]; }
    }
    const float g = gg[0];

    // ---- initial state into LDS (pad rows stay zero forever) ----
    xy[tid] = (tid < NN) ? make_float2(x0[tid], y0[tid]) : make_float2(0.f, 0.f);
    __syncthreads();

    // prefetched noise for step 0
    float2 nz = make_float2(0.f, 0.f);
    if (myrow >= 0) nz = *(const float2*)(noise + 2 * (size_t)myrow);

    // persistent ping-pong poll buffers: live across the whole t-loop so an
    // in-flight straggler load can never land in a reused register.
    u32x4 va = {0u, 0u, 0u, 0u}, vb = {0u, 0u, 0u, 0u};

    for (int t = 0; t < TT; ++t) {
        const int p = t & 1;
        // prefetch next step's noise (hidden under the matvec)
        float2 nz_next = make_float2(0.f, 0.f);
        if (myrow >= 0 && t + 1 < TT)
            nz_next = *(const float2*)(noise + (size_t)(t + 1) * (2 * NN) + 2 * (size_t)myrow);

        // ---- partial matvec: 4 rows x 16 strided cols per thread ----
        float2 acc[RPT];
#pragma unroll
        for (int r = 0; r < RPT; ++r) acc[r] = make_float2(0.f, 0.f);
#pragma unroll
        for (int c = 0; c < CPT; ++c) {
            float2 w = xy[cgrp + 32 * c];
#pragma unroll
            for (int r = 0; r < RPT; ++r) {
                acc[r].x += scr[r][c] * w.x;
                acc[r].y += scr[r][c] * w.y;
            }
        }
        // ---- reduce across the 32 column-group lanes ----
#pragma unroll
        for (int m = 16; m >= 1; m >>= 1) {
#pragma unroll
            for (int r = 0; r < RPT; ++r) {
                acc[r].x += __shfl_xor(acc[r].x, m, 32);
                acc[r].y += __shfl_xor(acc[r].y, m, 32);
            }
        }

        // ---- finalize + publish tagged 16B packet (lanes cgrp<RPT) ----
        if (myrow >= 0) {
            float sx = (cgrp == 0) ? acc[0].x : (cgrp == 1) ? acc[1].x
                     : (cgrp == 2) ? acc[2].x : acc[3].x;
            float sy = (cgrp == 0) ? acc[0].y : (cgrp == 1) ? acc[1].y
                     : (cgrp == 2) ? acc[2].y : acc[3].y;
            float2 cur = xy[myrow];
            float r2 = cur.x * cur.x + cur.y * cur.y;
            float cx = sx - deg_i * cur.x;
            float cy = sy - deg_i * cur.y;
            float dx = (a_i - r2) * cur.x - om_i * cur.y + g * cx;
            float dy = (a_i - r2) * cur.y + om_i * cur.x + g * cy;
            float xn = cur.x + DTC * dx + SQDTC * nz.x;
            float yn = cur.y + DTC * dy + SQDTC * nz.y;
            out[(size_t)t * NN + myrow] = xn;
            u32x4 pkt = { __float_as_uint(xn), (unsigned)(t + 1),
                          __float_as_uint(yn), (unsigned)(t + 1) };
            store_coh_u128(&pub[(size_t)p * NPAD + myrow], pkt);
        }
        nz = nz_next;

        if (t == TT - 1) break;   // uniform across grid

        // protect xy: all matvec/finalize reads done before overwrite
        __syncthreads();

        // ---- gather: ping-pong poll, two loads in flight to DISTINCT quads,
        //      vmcnt(1) waits only the older -> sampling period ~RTT/2.
        //      Stale tag (<= t-1) can never satisfy >= t+1, so a mis-sample
        //      only costs one extra iteration, never wrong data. ----
        if (tid < NN) {
            const u32x4* slot = &pub[(size_t)p * NPAD + tid];
            const int need = t + 1;
            asm volatile("global_load_dwordx4 %0, %2, off sc0 sc1\n\t"
                         "global_load_dwordx4 %1, %2, off sc0 sc1"
                         : "+v"(va), "+v"(vb) : "v"(slot) : "memory");
            u32x4 res;
            for (;;) {
                asm volatile("s_waitcnt vmcnt(1)" ::: "memory");
                __builtin_amdgcn_sched_barrier(0);
                if ((int)va.y >= need && (int)va.w >= need) { res = va; break; }
                asm volatile("global_load_dwordx4 %0, %1, off sc0 sc1"
                             : "+v"(va) : "v"(slot) : "memory");
                asm volatile("s_waitcnt vmcnt(1)" ::: "memory");
                __builtin_amdgcn_sched_barrier(0);
                if ((int)vb.y >= need && (int)vb.w >= need) { res = vb; break; }
                asm volatile("global_load_dwordx4 %0, %1, off sc0 sc1"
                             : "+v"(vb) : "v"(slot) : "memory");
            }
            xy[tid] = make_float2(__uint_as_float(res.x), __uint_as_float(res.z));
        }
        __syncthreads();
    }

    // keep ping-pong buffers alive to the end: the last straggler load must
    // not land in a register the compiler reused.
    asm volatile("" :: "v"(va), "v"(vb));
}

extern "C" void kernel_launch(void* const* d_in, const int* in_sizes, int n_in,
                              void* d_out, int out_size, void* d_ws, size_t ws_size,
                              hipStream_t stream) {
    const float* sc = (const float*)d_in[0];
    const float* x0 = (const float*)d_in[1];
    const float* y0 = (const float*)d_in[2];
    const float* aa = (const float*)d_in[3];
    const float* om = (const float*)d_in[4];
    const float* nz = (const float*)d_in[5];
    const float* gg = (const float*)d_in[6];
    float* out = (float*)d_out;

    u32x4* pub = (u32x4*)d_ws;   // 2*NPAD*16 = 16 KB

    hipLaunchKernelGGL(hopf_init_ws, dim3(1), dim3(1024), 0, stream, pub);
    hipLaunchKernelGGL(hopf_main, dim3(NBLK), dim3(TPB), 0, stream,
                       sc, x0, y0, aa, om, nz, gg, out, pub);
}

// Round 13
// 43015.784 us; speedup vs baseline: 1.3769x; 1.0453x over previous
//
#include <hip/hip_runtime.h>

#define NN    500
#define TT    20000
#define NPAD  512
#define NBLK  8
#define NROW  64        // padded rows per block
#define TPB   512
#define RPT   4         // rows per thread
#define CPT   16        // cols per thread (strided by 32)
#define SLOTW 4         // u32x4 units per slot (64B line per row slot)
#define DTC   0.05f
#define SQDTC 0.22360679774997896f

typedef unsigned int u32x4 __attribute__((ext_vector_type(4)));

// ---------------------------------------------------------------------------
// Fully-coherent 16B accessors (sc0 sc1, proven R2/R5). Packet (x,tag,y,tag):
// each 8B half = one data word + one tag copy. Each row slot owns a FULL 64B
// line (SLOTW*16B) so at most 8 pollers + 1 writer touch any line.
// ---------------------------------------------------------------------------
__device__ __forceinline__ void store_coh_u128(u32x4* p, u32x4 v) {
    asm volatile("global_store_dwordx4 %0, %1, off sc0 sc1" :: "v"(p), "v"(v) : "memory");
}
__device__ __forceinline__ u32x4 load_coh_u128(const u32x4* p) {
    u32x4 v;
    asm volatile("global_load_dwordx4 %0, %1, off sc0 sc1\n\t"
                 "s_waitcnt vmcnt(0)" : "=v"(v) : "v"(p) : "memory");
    return v;
}

// ws layout: pub[2][NPAD] slots, each SLOTW u32x4 (64B) = 64 KB total
__global__ __launch_bounds__(1024) void hopf_init_ws(u32x4* pub) {
    int i = blockIdx.x * blockDim.x + threadIdx.x;
    if (i < 2 * NPAD * SLOTW) pub[i] = (u32x4){0u, 0u, 0u, 0u};
}

__global__ __launch_bounds__(TPB) void hopf_main(
    const float* __restrict__ sc, const float* __restrict__ x0,
    const float* __restrict__ y0, const float* __restrict__ aa,
    const float* __restrict__ om, const float* __restrict__ noise,
    const float* __restrict__ gg, float* __restrict__ out,
    u32x4* __restrict__ pub)
{
    const int tid  = threadIdx.x;
    const int blk  = blockIdx.x;
    const int cgrp = tid & 31;       // 32 column groups
    const int rgrp = tid >> 5;       // 16 row groups of RPT rows
    const int r0   = blk * NROW + rgrp * RPT;   // padded global row base

    __shared__ __align__(16) float2 xy[NPAD];   // full padded state (x,y)
    __shared__ __align__(16) float2 own[NROW];  // this block's fresh rows (LDS bypass)

    // ---- sc slice -> registers.  col(c) = cgrp + 32*c ----
    float scr[RPT][CPT];
#pragma unroll
    for (int r = 0; r < RPT; ++r) {
        int row = r0 + r;
#pragma unroll
        for (int c = 0; c < CPT; ++c) {
            int col = cgrp + 32 * c;
            scr[r][c] = (row < NN && col < NN) ? sc[row * NN + col] : 0.0f;
        }
    }

    // ---- deg per row ----
    float dsum[RPT];
#pragma unroll
    for (int r = 0; r < RPT; ++r) {
        float s = 0.f;
#pragma unroll
        for (int c = 0; c < CPT; ++c) s += scr[r][c];
        dsum[r] = s;
    }
#pragma unroll
    for (int m = 16; m >= 1; m >>= 1) {
#pragma unroll
        for (int r = 0; r < RPT; ++r) dsum[r] += __shfl_xor(dsum[r], m, 32);
    }

    // ---- pin the sc slice (optimizer cannot demote/rematerialize) ----
#pragma unroll
    for (int r = 0; r < RPT; ++r)
#pragma unroll
        for (int c = 0; c < CPT; ++c)
            asm volatile("" : "+v"(scr[r][c]));

    // ---- per-finalize-lane constants (lanes cgrp<RPT own row r0+cgrp) ----
    float a_i = 0.f, om_i = 0.f, deg_i = 0.f;
    int myrow = -1;
    if (cgrp < RPT) {
        int row = r0 + cgrp;
        deg_i = (cgrp == 0) ? dsum[0] : (cgrp == 1) ? dsum[1]
              : (cgrp == 2) ? dsum[2] : dsum[3];
        if (row < NN) { myrow = row; a_i = aa[row]; om_i = om[row]; }
    }
    const float g = gg[0];
    const int obase = blk * NROW;    // own-row range [obase, obase+NROW)

    // ---- initial state into LDS (pad rows stay zero forever) ----
    xy[tid] = (tid < NN) ? make_float2(x0[tid], y0[tid]) : make_float2(0.f, 0.f);
    __syncthreads();

    // prefetched noise for step 0
    float2 nz = make_float2(0.f, 0.f);
    if (myrow >= 0) nz = *(const float2*)(noise + 2 * (size_t)myrow);

    for (int t = 0; t < TT; ++t) {
        const int p = t & 1;
        // prefetch next step's noise (hidden under the matvec)
        float2 nz_next = make_float2(0.f, 0.f);
        if (myrow >= 0 && t + 1 < TT)
            nz_next = *(const float2*)(noise + (size_t)(t + 1) * (2 * NN) + 2 * (size_t)myrow);

        // ---- partial matvec: 4 rows x 16 strided cols per thread ----
        float2 acc[RPT];
#pragma unroll
        for (int r = 0; r < RPT; ++r) acc[r] = make_float2(0.f, 0.f);
#pragma unroll
        for (int c = 0; c < CPT; ++c) {
            float2 w = xy[cgrp + 32 * c];
#pragma unroll
            for (int r = 0; r < RPT; ++r) {
                acc[r].x += scr[r][c] * w.x;
                acc[r].y += scr[r][c] * w.y;
            }
        }
        // ---- reduce across the 32 column-group lanes ----
#pragma unroll
        for (int m = 16; m >= 1; m >>= 1) {
#pragma unroll
            for (int r = 0; r < RPT; ++r) {
                acc[r].x += __shfl_xor(acc[r].x, m, 32);
                acc[r].y += __shfl_xor(acc[r].y, m, 32);
            }
        }

        // ---- finalize + publish tagged 64B-line slot (lanes cgrp<RPT) ----
        if (myrow >= 0) {
            float sx = (cgrp == 0) ? acc[0].x : (cgrp == 1) ? acc[1].x
                     : (cgrp == 2) ? acc[2].x : acc[3].x;
            float sy = (cgrp == 0) ? acc[0].y : (cgrp == 1) ? acc[1].y
                     : (cgrp == 2) ? acc[2].y : acc[3].y;
            float2 cur = xy[myrow];
            float r2 = cur.x * cur.x + cur.y * cur.y;
            float cx = sx - deg_i * cur.x;
            float cy = sy - deg_i * cur.y;
            float dx = (a_i - r2) * cur.x - om_i * cur.y + g * cx;
            float dy = (a_i - r2) * cur.y + om_i * cur.x + g * cy;
            float xn = cur.x + DTC * dx + SQDTC * nz.x;
            float yn = cur.y + DTC * dy + SQDTC * nz.y;
            out[(size_t)t * NN + myrow] = xn;
            u32x4 pkt = { __float_as_uint(xn), (unsigned)(t + 1),
                          __float_as_uint(yn), (unsigned)(t + 1) };
            store_coh_u128(&pub[((size_t)p * NPAD + myrow) * SLOTW], pkt);
            own[myrow - obase] = make_float2(xn, yn);   // LDS bypass for own block
        }
        nz = nz_next;

        if (t == TT - 1) break;   // uniform across grid

        // protect xy: all matvec/finalize reads done before overwrite;
        // also makes own[] visible block-wide
        __syncthreads();

        // ---- gather: own rows from LDS; foreign rows via single-outstanding
        //      poll of the row's private 64B line ----
        if (tid < NN) {
            if (tid >= obase && tid < obase + NROW) {
                xy[tid] = own[tid - obase];
            } else {
                const u32x4* slot = &pub[((size_t)p * NPAD + tid) * SLOTW];
                u32x4 v;
                do {
                    v = load_coh_u128(slot);
                } while ((int)v.y < t + 1 || (int)v.w < t + 1);
                xy[tid] = make_float2(__uint_as_float(v.x), __uint_as_float(v.z));
            }
        }
        __syncthreads();
    }
}

extern "C" void kernel_launch(void* const* d_in, const int* in_sizes, int n_in,
                              void* d_out, int out_size, void* d_ws, size_t ws_size,
                              hipStream_t stream) {
    const float* sc = (const float*)d_in[0];
    const float* x0 = (const float*)d_in[1];
    const float* y0 = (const float*)d_in[2];
    const float* aa = (const float*)d_in[3];
    const float* om = (const float*)d_in[4];
    const float* nz = (const float*)d_in[5];
    const float* gg = (const float*)d_in[6];
    float* out = (float*)d_out;

    u32x4* pub = (u32x4*)d_ws;   // 2*NPAD*SLOTW*16 = 64 KB

    hipLaunchKernelGGL(hopf_init_ws, dim3(4), dim3(1024), 0, stream, pub);
    hipLaunchKernelGGL(hopf_main, dim3(NBLK), dim3(TPB), 0, stream,
                       sc, x0, y0, aa, om, nz, gg, out, pub);
}